// Round 23
// baseline (375.300 us; speedup 1.0000x reference)
//
#include <hip/hip_runtime.h>
#include <hip/hip_bf16.h>

// Transformer-XL RelPartialLearnableMultiHeadAttn — round 23: K/V frags via L2.
// attn's K and Vt LDS tiles were pure broadcast (all 8 waves read identical
// fragments, L2-resident via XCD colocation) -> read them directly from global
// (identical bytes), deleting Klds/Vtlds. LDS pipe (the bottleneck: ~77%
// issue-utilization) loses ~45% of its ops; the idle VMEM pipe absorbs 16
// L2-hit loads/wave-tile. LDS 56->40KB, VGPR -8 -> launch_bounds(512,3)
// (3 blocks/CU). Everything else = round 22 (4 launches, fused GEMMs).

#define QLEN 1024
#define MLEN 1024
#define KLEN 2048
#define BSZ 8
#define DMODEL 512
#define NHEAD 8
#define DHEAD 64
#define RPAD 2176
#define QSC  0.18033688011112042f   // SCALE * log2(e)
#define RTHR 11.54f                 // 8 nats in log2 units
#define LN2F 0.6931471805599453f

// workspace byte offsets
#define B_QW   0u
#define B_QR   8388608u
#define B_K    16777216u
#define B_VT   33554432u     // bf16 [bn][64][2048], j pi-permuted within 64-tiles
#define B_R    50331648u
#define B_AVB  52559872u
#define B_ENT  60948480u
#define B_WQT  77729792u
#define B_WRT  81399808u
#define B_WOT  81924096u

typedef short bf16x8 __attribute__((ext_vector_type(8)));
typedef float f32x4  __attribute__((ext_vector_type(4)));

#define SWZ(row, byte) ((((row) << 7) + (((((byte) >> 4) ^ ((row) & 7)) << 4)) + ((byte) & 15)))

__device__ __forceinline__ unsigned short f2bf(float f) {
    union { float f; unsigned int u; } v; v.f = f;
    unsigned int r = v.u + 0x7FFFu + ((v.u >> 16) & 1u);
    return (unsigned short)(r >> 16);
}

// ---- transpose+cast all three weights (z=0..2) + R zero-pad (z=3) ---------
__global__ __launch_bounds__(256) void tcvt3(const float* __restrict__ Wqkv,
                                             const float* __restrict__ Wr,
                                             const float* __restrict__ Wo,
                                             unsigned short* __restrict__ WQT,
                                             unsigned short* __restrict__ WRT,
                                             unsigned short* __restrict__ WOT,
                                             unsigned short* __restrict__ Rg) {
    if (blockIdx.z == 3) {
        int idx = blockIdx.x * 256 + threadIdx.x;
        if (blockIdx.y != 0 || blockIdx.x >= 32) return;
        int n = idx >> 10, o = idx & 1023;
        *reinterpret_cast<uint4*>(Rg + ((size_t)n * RPAD + KLEN) * 64 + o * 8) =
            make_uint4(0, 0, 0, 0);
        return;
    }
    const float* S; unsigned short* D; int C;
    if (blockIdx.z == 0)      { S = Wqkv; D = WQT; C = 1536; }
    else if (blockIdx.z == 1) { S = Wr;   D = WRT; C = 512;  }
    else                      { S = Wo;   D = WOT; C = 512;  }
    int bx = blockIdx.x * 32;
    if (bx >= C) return;
    int by = blockIdx.y * 32;
    __shared__ float t[32][33];
    int x = threadIdx.x & 31, y = threadIdx.x >> 5;
    #pragma unroll
    for (int q = 0; q < 4; ++q)
        t[y + q * 8][x] = S[(size_t)(by + y + q * 8) * C + bx + x];
    __syncthreads();
    #pragma unroll
    for (int q = 0; q < 4; ++q)
        D[(size_t)(bx + y + q * 8) * 512 + by + x] = f2bf(t[x][y + q * 8]);
}

// ---------------------------------------------------------------------------
// bf16 MFMA GEMM (round-22 structure, unchanged).
// ---------------------------------------------------------------------------
template<int MODE>
__global__ __launch_bounds__(256) void gemm_mfma(const float* __restrict__ Afa,
                                                 const float* __restrict__ Afb,
                                                 const float* __restrict__ Rsrc,
                                                 const unsigned short* __restrict__ Abf,
                                                 const unsigned short* __restrict__ BtQ,
                                                 const unsigned short* __restrict__ BtR,
                                                 const float* __restrict__ rwb,
                                                 const float* __restrict__ rrb,
                                                 unsigned short* __restrict__ QW,
                                                 unsigned short* __restrict__ QR,
                                                 unsigned short* __restrict__ Kg,
                                                 unsigned short* __restrict__ VT,
                                                 unsigned short* __restrict__ Rg,
                                                 const float* __restrict__ ent,
                                                 float* __restrict__ Cout) {
    bool isR = false;
    int n0, m0;
    if (MODE == 0) {
        if (blockIdx.y >= 128) {
            int id2 = blockIdx.x + 12 * (blockIdx.y - 128);
            if (id2 >= 64) return;
            isR = true;
            n0 = (id2 & 3) * 128;
            m0 = (id2 >> 2) * 128;
        } else {
            int id = blockIdx.x + 12 * blockIdx.y;
            int xcd = id & 7, u = id >> 3;
            n0 = (u % 12) * 128;
            m0 = (16 * xcd + u / 12) * 128;
        }
    } else {
        if (blockIdx.y == 64) {
            if (blockIdx.x == 0) {
                int n = threadIdx.x;
                if (n < NHEAD) {
                    float s = 0.f;
                    for (int b = 0; b < BSZ; ++b)
                        for (int it = 0; it < 8; ++it)
                            s += ent[(b * NHEAD + n) * 8 + it];
                    Cout[(size_t)QLEN * BSZ * DMODEL + n] = s / (float)(QLEN * BSZ);
                }
            }
            return;
        }
        int id = blockIdx.x + 4 * blockIdx.y;
        int xcd = id & 7, u = id >> 3;
        n0 = (u % 4) * 128;
        m0 = (8 * xcd + u / 4) * 128;
    }

    __shared__ unsigned short Als[2][128][72];
    __shared__ unsigned short Bls[2][128][72];
    const int tid = threadIdx.x;
    const int wv = tid >> 6, lane = tid & 63, lg = lane >> 4, lc = lane & 15;
    const int wr = wv >> 1, wc = wv & 1;

    const float* Af = nullptr;
    const unsigned short* Bt;
    if (MODE == 0) {
        if (isR) { Af = Rsrc + (size_t)m0 * 512; Bt = BtR; }
        else {
            Af = (m0 < 8192) ? (Afa + (size_t)m0 * 512)
                             : (Afb + (size_t)(m0 - 8192) * 512);
            Bt = BtQ;
        }
    } else {
        Bt = BtQ;
    }

    auto STAGE = [&](int buf, int k0) {
        #pragma unroll
        for (int q = 0; q < 4; ++q) {
            int c = q * 256 + tid;
            int row = c >> 3, off = (c & 7) * 8;
            if (MODE == 0) {
                const float* s = Af + (size_t)row * 512 + k0 + off;
                float4 v0 = *reinterpret_cast<const float4*>(s);
                float4 v1 = *reinterpret_cast<const float4*>(s + 4);
                unsigned int u0, u1, u2, u3;
                asm("v_cvt_pk_bf16_f32 %0, %1, %2" : "=v"(u0) : "v"(v0.x), "v"(v0.y));
                asm("v_cvt_pk_bf16_f32 %0, %1, %2" : "=v"(u1) : "v"(v0.z), "v"(v0.w));
                asm("v_cvt_pk_bf16_f32 %0, %1, %2" : "=v"(u2) : "v"(v1.x), "v"(v1.y));
                asm("v_cvt_pk_bf16_f32 %0, %1, %2" : "=v"(u3) : "v"(v1.z), "v"(v1.w));
                *reinterpret_cast<uint4*>(&Als[buf][row][off]) = make_uint4(u0, u1, u2, u3);
            } else {
                *reinterpret_cast<uint4*>(&Als[buf][row][off]) =
                    *reinterpret_cast<const uint4*>(Abf + (size_t)(m0 + row) * 512 + k0 + off);
            }
            *reinterpret_cast<uint4*>(&Bls[buf][row][off]) =
                *reinterpret_cast<const uint4*>(Bt + (size_t)(n0 + row) * 512 + k0 + off);
        }
    };

    f32x4 acc[4][4];
    #pragma unroll
    for (int mi = 0; mi < 4; ++mi)
        #pragma unroll
        for (int ni = 0; ni < 4; ++ni)
            acc[mi][ni] = (f32x4){0.f, 0.f, 0.f, 0.f};

    STAGE(0, 0);
    __syncthreads();
    for (int ks = 0; ks < 8; ++ks) {
        const int cur = ks & 1;
        if (ks < 7) STAGE(cur ^ 1, (ks + 1) * 64);
        #pragma unroll
        for (int kk = 0; kk < 2; ++kk) {
            bf16x8 af[4], bfr[4];
            #pragma unroll
            for (int mi = 0; mi < 4; ++mi)
                af[mi] = *reinterpret_cast<const bf16x8*>(&Als[cur][64 * wr + 16 * mi + lc][32 * kk + lg * 8]);
            #pragma unroll
            for (int ni = 0; ni < 4; ++ni)
                bfr[ni] = *reinterpret_cast<const bf16x8*>(&Bls[cur][64 * wc + 16 * ni + lc][32 * kk + lg * 8]);
            #pragma unroll
            for (int mi = 0; mi < 4; ++mi)
                #pragma unroll
                for (int ni = 0; ni < 4; ++ni)
                    acc[mi][ni] = __builtin_amdgcn_mfma_f32_16x16x32_bf16(af[mi], bfr[ni], acc[mi][ni], 0, 0, 0);
        }
        __syncthreads();
    }

    #pragma unroll
    for (int mi = 0; mi < 4; ++mi) {
        #pragma unroll
        for (int ni = 0; ni < 4; ++ni) {
            const int n = n0 + 64 * wc + 16 * ni + lc;
            float bw = 0.f, br = 0.f;
            int region = 0, hn = 0, d = 0;
            if (MODE == 0 && !isR) {
                region = n >> 9; int cr = n & 511; hn = cr >> 6; d = cr & 63;
                if (region == 0) { bw = rwb[hn * 64 + d]; br = rrb[hn * 64 + d]; }
            }
            #pragma unroll
            for (int reg = 0; reg < 4; ++reg) {
                const int m = m0 + 64 * wr + 16 * mi + lg * 4 + reg;
                const float val = acc[mi][ni][reg];
                if (MODE == 0) {
                    if (isR) {
                        Rg[((size_t)(n >> 6) * RPAD + m) * 64 + (n & 63)] = f2bf(val);
                    } else {
                        int t = m >> 3, b = m & 7, bn = b * 8 + hn;
                        if (region == 0) {
                            if (t >= MLEN) {
                                size_t base = ((size_t)bn * QLEN + (t - MLEN)) * 64 + d;
                                QW[base] = f2bf((val + bw) * QSC);
                                QR[base] = f2bf((val + br) * QSC);
                            }
                        } else if (region == 1) {
                            Kg[((size_t)bn * KLEN + t) * 64 + d] = f2bf(val);
                        } else {
                            int jt = t & 63, bb = jt >> 4, ll = jt & 15;
                            int pj = (bb < 2) ? (2 * ll + bb) : (32 + 2 * ll + (bb - 2));
                            VT[((size_t)bn * 64 + d) * KLEN + (t & ~63) + pj] = f2bf(val);
                        }
                    }
                } else {
                    Cout[(size_t)m * 512 + n] = val;
                }
            }
        }
    }
}

// ---------------------------------------------------------------------------
// MFMA attention: K/V fragments read directly from global (L2-resident via
// XCD colocation); LDS holds only R band + P. 3 blocks/CU. grid (8, 64).
// ---------------------------------------------------------------------------
__global__ __launch_bounds__(512, 3) void attn_mfma(const unsigned short* __restrict__ QWg,
                                                    const unsigned short* __restrict__ QRg,
                                                    const unsigned short* __restrict__ Kg,
                                                    const unsigned short* __restrict__ VTg,
                                                    const unsigned short* __restrict__ Rg,
                                                    unsigned short* __restrict__ AVB,
                                                    float* __restrict__ ENT) {
    __shared__ __attribute__((aligned(16))) unsigned short Rblds[192 * 64];  // 24 KB
    __shared__ __attribute__((aligned(16))) unsigned short Plds[128 * 64];   // 16 KB

    const int tid = threadIdx.x;
    const int w = tid >> 6, lane = tid & 63, lg = lane >> 4, lc = lane & 15;
    const int n = blockIdx.x;                       // head = XCD slot (id % 8)
    const int b = blockIdx.y & 7;
    const int kq = blockIdx.y >> 3;
    const int iblk = (kq < 4) ? kq : 11 - kq;
    const int i0 = iblk * 128;
    const int bn = b * 8 + n;
    const int srow = tid >> 3;
    const int sch  = tid & 7;

    // ---- stage QW (Rblds) / QR (Plds) i-tiles, pull A-frags ----
    {
        const unsigned short* qwsrc = QWg + ((size_t)bn * QLEN + i0) * 64;
        const unsigned short* qrsrc = QRg + ((size_t)bn * QLEN + i0) * 64;
        #pragma unroll
        for (int q = 0; q < 2; ++q) {
            int row = srow + q * 64;
            *reinterpret_cast<uint4*>((char*)Rblds + SWZ(row, sch * 16)) =
                *reinterpret_cast<const uint4*>(qwsrc + (size_t)row * 64 + sch * 8);
            *reinterpret_cast<uint4*>((char*)Plds + SWZ(row, sch * 16)) =
                *reinterpret_cast<const uint4*>(qrsrc + (size_t)row * 64 + sch * 8);
        }
    }
    __syncthreads();
    bf16x8 aqw[2], aqr[2];
    #pragma unroll
    for (int k = 0; k < 2; ++k) {
        aqw[k] = *reinterpret_cast<const bf16x8*>((const char*)Rblds + SWZ(16 * w + lc, 64 * k + 16 * lg));
        aqr[k] = *reinterpret_cast<const bf16x8*>((const char*)Plds + SWZ(16 * w + lc, 64 * k + 16 * lg));
    }

    f32x4 Ofr[4];
    #pragma unroll
    for (int t = 0; t < 4; ++t) Ofr[t] = (f32x4){0.f, 0.f, 0.f, 0.f};
    float mreg[4] = {-1e30f, -1e30f, -1e30f, -1e30f};
    float lpart[4] = {0.f, 0.f, 0.f, 0.f};
    float tpart[4] = {0.f, 0.f, 0.f, 0.f};

    const int nj = 2 * iblk + 18;
    const unsigned short* kbase = Kg  + (size_t)bn * KLEN * 64;
    const unsigned short* vbase = VTg + (size_t)bn * 64 * KLEN;
    const unsigned short* rbase = Rg  + (size_t)n * RPAD * 64 + (size_t)(896 - i0) * 64;

    // ---- prologue: prefetch R tile 0 ----
    uint4 rr0, rr1, rr2;
    rr0 = *reinterpret_cast<const uint4*>(rbase + (size_t)(srow)       * 64 + sch * 8);
    rr1 = *reinterpret_cast<const uint4*>(rbase + (size_t)(srow + 64)  * 64 + sch * 8);
    rr2 = *reinterpret_cast<const uint4*>(rbase + (size_t)(srow + 128) * 64 + sch * 8);

    for (int jt = 0; jt < nj; ++jt) {
        const int j0 = jt * 64;
        __syncthreads();

        *reinterpret_cast<uint4*>((char*)Rblds + SWZ(srow,       sch * 16)) = rr0;
        *reinterpret_cast<uint4*>((char*)Rblds + SWZ(srow + 64,  sch * 16)) = rr1;
        *reinterpret_cast<uint4*>((char*)Rblds + SWZ(srow + 128, sch * 16)) = rr2;

        if (jt + 1 < nj) {
            const int j1 = j0 + 64;
            rr0 = *reinterpret_cast<const uint4*>(rbase + (size_t)(j1 + srow)       * 64 + sch * 8);
            rr1 = *reinterpret_cast<const uint4*>(rbase + (size_t)(j1 + srow + 64)  * 64 + sch * 8);
            rr2 = *reinterpret_cast<const uint4*>(rbase + (size_t)(j1 + srow + 128) * 64 + sch * 8);
        }

        asm volatile("s_waitcnt lgkmcnt(0)" ::: "memory");
        __builtin_amdgcn_sched_barrier(0);
        __builtin_amdgcn_s_barrier();
        asm volatile("" ::: "memory");
        __builtin_amdgcn_sched_barrier(0);

        __builtin_amdgcn_s_setprio(1);
        // ---- AC: K fragments direct from global (L2-hit) ----
        f32x4 sfr[4];
        #pragma unroll
        for (int bj = 0; bj < 4; ++bj) {
            f32x4 acc = (f32x4){0.f, 0.f, 0.f, 0.f};
            #pragma unroll
            for (int k = 0; k < 2; ++k) {
                bf16x8 bk = *reinterpret_cast<const bf16x8*>(
                    kbase + (size_t)(j0 + 16 * bj + lc) * 64 + 32 * k + 16 * lg);
                acc = __builtin_amdgcn_mfma_f32_16x16x32_bf16(aqw[k], bk, acc, 0, 0, 0);
            }
            sfr[bj] = acc;
        }
        // ---- BD strip (Rblds reads) ----
        f32x4 g[5];
        const int sb = 112 - 16 * w;
        #pragma unroll
        for (int cb = 0; cb < 5; ++cb) {
            g[cb] = (f32x4){0.f, 0.f, 0.f, 0.f};
            #pragma unroll
            for (int k = 0; k < 2; ++k) {
                bf16x8 br = *reinterpret_cast<const bf16x8*>((const char*)Rblds + SWZ(sb + 16 * cb + lc, 64 * k + 16 * lg));
                g[cb] = __builtin_amdgcn_mfma_f32_16x16x32_bf16(aqr[k], br, g[cb], 0, 0, 0);
            }
        }
        __builtin_amdgcn_s_setprio(0);

        // ---- diag gather + combine ----
        #pragma unroll
        for (int reg = 0; reg < 4; ++reg) {
            int r = lg * 4 + reg;
            int srcl = (lane & 48) | ((lc - r + 15) & 15);
            float gg[5];
            #pragma unroll
            for (int cb = 0; cb < 5; ++cb)
                gg[cb] = __shfl(g[cb][reg], srcl, 64);
            #pragma unroll
            for (int bj = 0; bj < 4; ++bj) {
                float gv = (lc <= r) ? gg[bj] : gg[bj + 1];
                sfr[bj][reg] = sfr[bj][reg] + gv;
            }
        }
        if (jt >= nj - 2) {
            #pragma unroll
            for (int bj = 0; bj < 4; ++bj)
                #pragma unroll
                for (int reg = 0; reg < 4; ++reg) {
                    int ii = 16 * w + lg * 4 + reg;
                    int jj = 16 * bj + lc;
                    if (j0 + jj > i0 + ii + MLEN) sfr[bj][reg] = -1e30f;
                }
        }

        // ---- defer-max online softmax (log2 domain) ----
        float pm[4];
        #pragma unroll
        for (int reg = 0; reg < 4; ++reg)
            pm[reg] = fmaxf(fmaxf(sfr[0][reg], sfr[1][reg]), fmaxf(sfr[2][reg], sfr[3][reg]));
        bool grow = (pm[0] > mreg[0] + RTHR) || (pm[1] > mreg[1] + RTHR) ||
                    (pm[2] > mreg[2] + RTHR) || (pm[3] > mreg[3] + RTHR);
        if (__any(grow)) {
            #pragma unroll
            for (int reg = 0; reg < 4; ++reg) {
                float gmax = pm[reg];
                gmax = fmaxf(gmax, __shfl_xor(gmax, 1));
                gmax = fmaxf(gmax, __shfl_xor(gmax, 2));
                gmax = fmaxf(gmax, __shfl_xor(gmax, 4));
                gmax = fmaxf(gmax, __shfl_xor(gmax, 8));
                float mo = mreg[reg], mn = fmaxf(mo, gmax);
                float fac = exp2f(mo - mn);
                lpart[reg] *= fac; tpart[reg] *= fac; mreg[reg] = mn;
                Ofr[0][reg] *= fac; Ofr[1][reg] *= fac;
                Ofr[2][reg] *= fac; Ofr[3][reg] *= fac;
            }
        }
        #pragma unroll
        for (int reg = 0; reg < 4; ++reg) {
            float mn = mreg[reg];
            int r = lg * 4 + reg;
            float ee[4];
            float le = 0.f, te = 0.f;
            #pragma unroll
            for (int bj = 0; bj < 4; ++bj) {
                ee[bj] = exp2f(sfr[bj][reg] - mn);
                le += ee[bj]; te += ee[bj] * sfr[bj][reg];
            }
            lpart[reg] += le;
            tpart[reg] += te;
            unsigned int p01, p23;
            asm("v_cvt_pk_bf16_f32 %0, %1, %2" : "=v"(p01) : "v"(ee[0]), "v"(ee[1]));
            asm("v_cvt_pk_bf16_f32 %0, %1, %2" : "=v"(p23) : "v"(ee[2]), "v"(ee[3]));
            *reinterpret_cast<unsigned int*>((char*)Plds + SWZ(16 * w + r, 4 * lc))      = p01;
            *reinterpret_cast<unsigned int*>((char*)Plds + SWZ(16 * w + r, 64 + 4 * lc)) = p23;
        }
        asm volatile("s_waitcnt lgkmcnt(0)" ::: "memory");
        __builtin_amdgcn_sched_barrier(0);

        // ---- PV: V fragments direct from global (pi K-order, L2-hit) ----
        __builtin_amdgcn_s_setprio(1);
        #pragma unroll
        for (int k = 0; k < 2; ++k) {
            bf16x8 ap = *reinterpret_cast<const bf16x8*>((const char*)Plds + SWZ(16 * w + lc, 64 * k + 16 * lg));
            #pragma unroll
            for (int ni = 0; ni < 4; ++ni) {
                bf16x8 bv = *reinterpret_cast<const bf16x8*>(
                    vbase + (size_t)(16 * ni + lc) * KLEN + j0 + 32 * k + 16 * lg);
                Ofr[ni] = __builtin_amdgcn_mfma_f32_16x16x32_bf16(ap, bv, Ofr[ni], 0, 0, 0);
            }
        }
        __builtin_amdgcn_s_setprio(0);
    }

    // ---- final l/t reduction ----
    float lred[4], tred[4];
    #pragma unroll
    for (int reg = 0; reg < 4; ++reg) {
        float l = lpart[reg], t = tpart[reg];
        l += __shfl_xor(l, 1); l += __shfl_xor(l, 2); l += __shfl_xor(l, 4); l += __shfl_xor(l, 8);
        t += __shfl_xor(t, 1); t += __shfl_xor(t, 2); t += __shfl_xor(t, 4); t += __shfl_xor(t, 8);
        lred[reg] = l; tred[reg] = t;
    }

    // ---- normalize + write attn_vec (bf16) ----
    #pragma unroll
    for (int reg = 0; reg < 4; ++reg) {
        int i = i0 + 16 * w + lg * 4 + reg;
        float inv = 1.f / lred[reg];
        unsigned short* dst = AVB + ((size_t)i * BSZ + b) * DMODEL + n * 64 + lc;
        dst[ 0] = f2bf(Ofr[0][reg] * inv);
        dst[16] = f2bf(Ofr[1][reg] * inv);
        dst[32] = f2bf(Ofr[2][reg] * inv);
        dst[48] = f2bf(Ofr[3][reg] * inv);
    }

    // ---- entropy partial: H = ln2 * (m2 + log2 l - t2/l) ----
    float h = 0.f;
    if (lc == 0) {
        #pragma unroll
        for (int reg = 0; reg < 4; ++reg)
            h += mreg[reg] + log2f(lred[reg]) - tred[reg] / lred[reg];
    }
    h += __shfl_xor(h, 1);  h += __shfl_xor(h, 2);  h += __shfl_xor(h, 4);
    h += __shfl_xor(h, 8);  h += __shfl_xor(h, 16); h += __shfl_xor(h, 32);
    __syncthreads();
    float* hred = reinterpret_cast<float*>(Plds);
    if (lane == 0) hred[w] = h;
    __syncthreads();
    if (tid == 0) {
        float s = 0.f;
        #pragma unroll
        for (int q = 0; q < 8; ++q) s += hred[q];
        ENT[bn * 8 + iblk] = s * LN2F;
    }
}

extern "C" void kernel_launch(void* const* d_in, const int* in_sizes, int n_in,
                              void* d_out, int out_size, void* d_ws, size_t ws_size,
                              hipStream_t stream) {
    const float* w    = (const float*)d_in[0];
    const float* r    = (const float*)d_in[1];
    const float* rwb  = (const float*)d_in[2];
    const float* rrb  = (const float*)d_in[3];
    const float* mems = (const float*)d_in[4];
    const float* Wqkv = (const float*)d_in[6];
    const float* Wr   = (const float*)d_in[7];
    const float* Wo   = (const float*)d_in[8];
    float* out = (float*)d_out;
    char*  wsb = (char*)d_ws;

    unsigned short* QW  = (unsigned short*)(wsb + B_QW);
    unsigned short* QR  = (unsigned short*)(wsb + B_QR);
    unsigned short* Kg  = (unsigned short*)(wsb + B_K);
    unsigned short* VT  = (unsigned short*)(wsb + B_VT);
    unsigned short* Rg  = (unsigned short*)(wsb + B_R);
    unsigned short* AVB = (unsigned short*)(wsb + B_AVB);
    float* ENT = (float*)(wsb + B_ENT);
    unsigned short* WQT = (unsigned short*)(wsb + B_WQT);
    unsigned short* WRT = (unsigned short*)(wsb + B_WRT);
    unsigned short* WOT = (unsigned short*)(wsb + B_WOT);

    // weight transposes + R pad (one launch)
    tcvt3<<<dim3(48, 16, 4), 256, 0, stream>>>(Wqkv, Wr, Wo, WQT, WRT, WOT, Rg);

    // QKV + R projections (one launch; y>=128 blocks do R)
    gemm_mfma<0><<<dim3(12, 134), 256, 0, stream>>>(mems, w, r, nullptr, WQT, WRT, rwb, rrb,
                                                    QW, QR, Kg, VT, Rg, nullptr, nullptr);

    // attention + entropy partials
    attn_mfma<<<dim3(8, 64), 512, 0, stream>>>(QW, QR, Kg, VT, Rg, AVB, ENT);

    // out-projection + entropy reduce (one launch; y==64 block reduces ENT)
    gemm_mfma<2><<<dim3(4, 65), 256, 0, stream>>>(nullptr, nullptr, nullptr, AVB, WOT, nullptr,
                                                  nullptr, nullptr, nullptr, nullptr, nullptr,
                                                  nullptr, nullptr, ENT, out);
}

// Round 24
// 215.812 us; speedup vs baseline: 1.7390x; 1.7390x over previous
//
#include <hip/hip_runtime.h>
#include <hip/hip_bf16.h>

// Transformer-XL RelPartialLearnableMultiHeadAttn — round 24: REVERT to round 22
// (best measured: 216.0 us, absmax 1.5e-4). Round 23's K/V-from-L2 experiment
// regressed 124->283 us (MFMA operands on the VMEM critical path serialize on
// ~200cy L2 latency; staging loads pipeline, operand loads don't) — falsifier
// fired, revert. Structure: 4 launches; fused QKV+R GEMM (LDS dbuf, fused
// f32->bf16 convert, XCD colocation); attn 128-row tiles, swizzled LDS,
// reg-prefetch, BD strip + shfl diag gather, defer-max exp2 softmax,
// pi-packed P writes; out-proj + entropy-reduce fused.

#define QLEN 1024
#define MLEN 1024
#define KLEN 2048
#define BSZ 8
#define DMODEL 512
#define NHEAD 8
#define DHEAD 64
#define RPAD 2176
#define QSC  0.18033688011112042f   // SCALE * log2(e)
#define RTHR 11.54f                 // 8 nats in log2 units
#define LN2F 0.6931471805599453f

// workspace byte offsets
#define B_QW   0u
#define B_QR   8388608u
#define B_K    16777216u
#define B_VT   33554432u     // bf16 [bn][64][2048], j pi-permuted within 64-tiles
#define B_R    50331648u
#define B_AVB  52559872u
#define B_ENT  60948480u
#define B_WQT  77729792u
#define B_WRT  81399808u
#define B_WOT  81924096u

typedef short bf16x8 __attribute__((ext_vector_type(8)));
typedef float f32x4  __attribute__((ext_vector_type(4)));

#define SWZ(row, byte) ((((row) << 7) + (((((byte) >> 4) ^ ((row) & 7)) << 4)) + ((byte) & 15)))

__device__ __forceinline__ unsigned short f2bf(float f) {
    union { float f; unsigned int u; } v; v.f = f;
    unsigned int r = v.u + 0x7FFFu + ((v.u >> 16) & 1u);
    return (unsigned short)(r >> 16);
}

// ---- transpose+cast all three weights (z=0..2) + R zero-pad (z=3) ---------
__global__ __launch_bounds__(256) void tcvt3(const float* __restrict__ Wqkv,
                                             const float* __restrict__ Wr,
                                             const float* __restrict__ Wo,
                                             unsigned short* __restrict__ WQT,
                                             unsigned short* __restrict__ WRT,
                                             unsigned short* __restrict__ WOT,
                                             unsigned short* __restrict__ Rg) {
    if (blockIdx.z == 3) {   // zero pad rows 2048..2175 of Rg (32 x-blocks used)
        int idx = blockIdx.x * 256 + threadIdx.x;
        if (blockIdx.y != 0 || blockIdx.x >= 32) return;
        int n = idx >> 10, o = idx & 1023;
        *reinterpret_cast<uint4*>(Rg + ((size_t)n * RPAD + KLEN) * 64 + o * 8) =
            make_uint4(0, 0, 0, 0);
        return;
    }
    const float* S; unsigned short* D; int C;
    if (blockIdx.z == 0)      { S = Wqkv; D = WQT; C = 1536; }
    else if (blockIdx.z == 1) { S = Wr;   D = WRT; C = 512;  }
    else                      { S = Wo;   D = WOT; C = 512;  }
    int bx = blockIdx.x * 32;
    if (bx >= C) return;
    int by = blockIdx.y * 32;
    __shared__ float t[32][33];
    int x = threadIdx.x & 31, y = threadIdx.x >> 5;
    #pragma unroll
    for (int q = 0; q < 4; ++q)
        t[y + q * 8][x] = S[(size_t)(by + y + q * 8) * C + bx + x];
    __syncthreads();
    #pragma unroll
    for (int q = 0; q < 4; ++q)
        D[(size_t)(bx + y + q * 8) * 512 + by + x] = f2bf(t[x][y + q * 8]);
}

// ---------------------------------------------------------------------------
// bf16 MFMA GEMM, LDS double-buffered. MODE 0 grid (12,134): y<128 = QKV
// (fused f32 convert, XCD-colocated 16*xcd band, pi-permuted VT epilogue);
// y>=128 = R projection (64 blocks, r @ WRT^T -> Rg). MODE 2 grid (4,65):
// y<64 = out-proj (AVB bf16 -> f32 out, colocated); y==64 = entropy reduce.
// ---------------------------------------------------------------------------
template<int MODE>
__global__ __launch_bounds__(256) void gemm_mfma(const float* __restrict__ Afa,
                                                 const float* __restrict__ Afb,
                                                 const float* __restrict__ Rsrc,
                                                 const unsigned short* __restrict__ Abf,
                                                 const unsigned short* __restrict__ BtQ,
                                                 const unsigned short* __restrict__ BtR,
                                                 const float* __restrict__ rwb,
                                                 const float* __restrict__ rrb,
                                                 unsigned short* __restrict__ QW,
                                                 unsigned short* __restrict__ QR,
                                                 unsigned short* __restrict__ Kg,
                                                 unsigned short* __restrict__ VT,
                                                 unsigned short* __restrict__ Rg,
                                                 const float* __restrict__ ent,
                                                 float* __restrict__ Cout) {
    bool isR = false;
    int n0, m0;
    if (MODE == 0) {
        if (blockIdx.y >= 128) {            // R-projection rider blocks
            int id2 = blockIdx.x + 12 * (blockIdx.y - 128);
            if (id2 >= 64) return;
            isR = true;
            n0 = (id2 & 3) * 128;
            m0 = (id2 >> 2) * 128;          // panels 0..15 of r (M=2048)
        } else {
            int id = blockIdx.x + 12 * blockIdx.y;
            int xcd = id & 7, u = id >> 3;  // u in [0,192)
            n0 = (u % 12) * 128;
            m0 = (16 * xcd + u / 12) * 128; // m-panel in [0,128), bijective
        }
    } else {                                // MODE 2
        if (blockIdx.y == 64) {             // entropy-reduce rider block
            if (blockIdx.x == 0) {
                int n = threadIdx.x;
                if (n < NHEAD) {
                    float s = 0.f;
                    for (int b = 0; b < BSZ; ++b)
                        for (int it = 0; it < 8; ++it)
                            s += ent[(b * NHEAD + n) * 8 + it];
                    Cout[(size_t)QLEN * BSZ * DMODEL + n] = s / (float)(QLEN * BSZ);
                }
            }
            return;
        }
        int id = blockIdx.x + 4 * blockIdx.y;
        int xcd = id & 7, u = id >> 3;      // u in [0,32)
        n0 = (u % 4) * 128;
        m0 = (8 * xcd + u / 4) * 128;       // m-panel in [0,64)
    }

    __shared__ unsigned short Als[2][128][72];
    __shared__ unsigned short Bls[2][128][72];
    const int tid = threadIdx.x;
    const int wv = tid >> 6, lane = tid & 63, lg = lane >> 4, lc = lane & 15;
    const int wr = wv >> 1, wc = wv & 1;

    const float* Af = nullptr;
    const unsigned short* Bt;
    if (MODE == 0) {
        if (isR) { Af = Rsrc + (size_t)m0 * 512; Bt = BtR; }
        else {
            Af = (m0 < 8192) ? (Afa + (size_t)m0 * 512)
                             : (Afb + (size_t)(m0 - 8192) * 512);
            Bt = BtQ;
        }
    } else {
        Bt = BtQ;
    }

    auto STAGE = [&](int buf, int k0) {
        #pragma unroll
        for (int q = 0; q < 4; ++q) {
            int c = q * 256 + tid;
            int row = c >> 3, off = (c & 7) * 8;
            if (MODE == 0) {
                const float* s = Af + (size_t)row * 512 + k0 + off;
                float4 v0 = *reinterpret_cast<const float4*>(s);
                float4 v1 = *reinterpret_cast<const float4*>(s + 4);
                unsigned int u0, u1, u2, u3;
                asm("v_cvt_pk_bf16_f32 %0, %1, %2" : "=v"(u0) : "v"(v0.x), "v"(v0.y));
                asm("v_cvt_pk_bf16_f32 %0, %1, %2" : "=v"(u1) : "v"(v0.z), "v"(v0.w));
                asm("v_cvt_pk_bf16_f32 %0, %1, %2" : "=v"(u2) : "v"(v1.x), "v"(v1.y));
                asm("v_cvt_pk_bf16_f32 %0, %1, %2" : "=v"(u3) : "v"(v1.z), "v"(v1.w));
                *reinterpret_cast<uint4*>(&Als[buf][row][off]) = make_uint4(u0, u1, u2, u3);
            } else {
                *reinterpret_cast<uint4*>(&Als[buf][row][off]) =
                    *reinterpret_cast<const uint4*>(Abf + (size_t)(m0 + row) * 512 + k0 + off);
            }
            *reinterpret_cast<uint4*>(&Bls[buf][row][off]) =
                *reinterpret_cast<const uint4*>(Bt + (size_t)(n0 + row) * 512 + k0 + off);
        }
    };

    f32x4 acc[4][4];
    #pragma unroll
    for (int mi = 0; mi < 4; ++mi)
        #pragma unroll
        for (int ni = 0; ni < 4; ++ni)
            acc[mi][ni] = (f32x4){0.f, 0.f, 0.f, 0.f};

    STAGE(0, 0);
    __syncthreads();
    for (int ks = 0; ks < 8; ++ks) {
        const int cur = ks & 1;
        if (ks < 7) STAGE(cur ^ 1, (ks + 1) * 64);
        #pragma unroll
        for (int kk = 0; kk < 2; ++kk) {
            bf16x8 af[4], bfr[4];
            #pragma unroll
            for (int mi = 0; mi < 4; ++mi)
                af[mi] = *reinterpret_cast<const bf16x8*>(&Als[cur][64 * wr + 16 * mi + lc][32 * kk + lg * 8]);
            #pragma unroll
            for (int ni = 0; ni < 4; ++ni)
                bfr[ni] = *reinterpret_cast<const bf16x8*>(&Bls[cur][64 * wc + 16 * ni + lc][32 * kk + lg * 8]);
            #pragma unroll
            for (int mi = 0; mi < 4; ++mi)
                #pragma unroll
                for (int ni = 0; ni < 4; ++ni)
                    acc[mi][ni] = __builtin_amdgcn_mfma_f32_16x16x32_bf16(af[mi], bfr[ni], acc[mi][ni], 0, 0, 0);
        }
        __syncthreads();
    }

    #pragma unroll
    for (int mi = 0; mi < 4; ++mi) {
        #pragma unroll
        for (int ni = 0; ni < 4; ++ni) {
            const int n = n0 + 64 * wc + 16 * ni + lc;
            float bw = 0.f, br = 0.f;
            int region = 0, hn = 0, d = 0;
            if (MODE == 0 && !isR) {
                region = n >> 9; int cr = n & 511; hn = cr >> 6; d = cr & 63;
                if (region == 0) { bw = rwb[hn * 64 + d]; br = rrb[hn * 64 + d]; }
            }
            #pragma unroll
            for (int reg = 0; reg < 4; ++reg) {
                const int m = m0 + 64 * wr + 16 * mi + lg * 4 + reg;
                const float val = acc[mi][ni][reg];
                if (MODE == 0) {
                    if (isR) {
                        Rg[((size_t)(n >> 6) * RPAD + m) * 64 + (n & 63)] = f2bf(val);
                    } else {
                        int t = m >> 3, b = m & 7, bn = b * 8 + hn;
                        if (region == 0) {
                            if (t >= MLEN) {
                                size_t base = ((size_t)bn * QLEN + (t - MLEN)) * 64 + d;
                                QW[base] = f2bf((val + bw) * QSC);
                                QR[base] = f2bf((val + br) * QSC);
                            }
                        } else if (region == 1) {
                            Kg[((size_t)bn * KLEN + t) * 64 + d] = f2bf(val);
                        } else {
                            // VT with pi: pi(16b+l) = b<2 ? 2l+b : 32+2l+(b-2)
                            int jt = t & 63, bb = jt >> 4, ll = jt & 15;
                            int pj = (bb < 2) ? (2 * ll + bb) : (32 + 2 * ll + (bb - 2));
                            VT[((size_t)bn * 64 + d) * KLEN + (t & ~63) + pj] = f2bf(val);
                        }
                    }
                } else {
                    Cout[(size_t)m * 512 + n] = val;
                }
            }
        }
    }
}

// ---------------------------------------------------------------------------
// MFMA attention (round-17 core). grid (8, 64).
// ---------------------------------------------------------------------------
__global__ __launch_bounds__(512, 2) void attn_mfma(const unsigned short* __restrict__ QWg,
                                                    const unsigned short* __restrict__ QRg,
                                                    const unsigned short* __restrict__ Kg,
                                                    const unsigned short* __restrict__ VTg,
                                                    const unsigned short* __restrict__ Rg,
                                                    unsigned short* __restrict__ AVB,
                                                    float* __restrict__ ENT) {
    __shared__ __attribute__((aligned(16))) unsigned short Klds[64 * 64];    //  8 KB
    __shared__ __attribute__((aligned(16))) unsigned short Rblds[192 * 64];  // 24 KB
    __shared__ __attribute__((aligned(16))) unsigned short Vtlds[64 * 64];   //  8 KB
    __shared__ __attribute__((aligned(16))) unsigned short Plds[128 * 64];   // 16 KB

    const int tid = threadIdx.x;
    const int w = tid >> 6, lane = tid & 63, lg = lane >> 4, lc = lane & 15;
    const int n = blockIdx.x;                       // head = XCD slot (id % 8)
    const int b = blockIdx.y & 7;
    const int kq = blockIdx.y >> 3;
    const int iblk = (kq < 4) ? kq : 11 - kq;
    const int i0 = iblk * 128;
    const int bn = b * 8 + n;
    const int srow = tid >> 3;
    const int sch  = tid & 7;

    {
        const unsigned short* qwsrc = QWg + ((size_t)bn * QLEN + i0) * 64;
        const unsigned short* qrsrc = QRg + ((size_t)bn * QLEN + i0) * 64;
        #pragma unroll
        for (int q = 0; q < 2; ++q) {
            int row = srow + q * 64;
            *reinterpret_cast<uint4*>((char*)Rblds + SWZ(row, sch * 16)) =
                *reinterpret_cast<const uint4*>(qwsrc + (size_t)row * 64 + sch * 8);
            *reinterpret_cast<uint4*>((char*)Plds + SWZ(row, sch * 16)) =
                *reinterpret_cast<const uint4*>(qrsrc + (size_t)row * 64 + sch * 8);
        }
    }
    __syncthreads();
    bf16x8 aqw[2], aqr[2];
    #pragma unroll
    for (int k = 0; k < 2; ++k) {
        aqw[k] = *reinterpret_cast<const bf16x8*>((const char*)Rblds + SWZ(16 * w + lc, 64 * k + 16 * lg));
        aqr[k] = *reinterpret_cast<const bf16x8*>((const char*)Plds + SWZ(16 * w + lc, 64 * k + 16 * lg));
    }

    f32x4 Ofr[4];
    #pragma unroll
    for (int t = 0; t < 4; ++t) Ofr[t] = (f32x4){0.f, 0.f, 0.f, 0.f};
    float mreg[4] = {-1e30f, -1e30f, -1e30f, -1e30f};
    float lpart[4] = {0.f, 0.f, 0.f, 0.f};
    float tpart[4] = {0.f, 0.f, 0.f, 0.f};

    const int nj = 2 * iblk + 18;
    const unsigned short* kbase = Kg  + (size_t)bn * KLEN * 64;
    const unsigned short* vbase = VTg + (size_t)bn * 64 * KLEN;
    const unsigned short* rbase = Rg  + (size_t)n * RPAD * 64 + (size_t)(896 - i0) * 64;

    uint4 kr0, vr0, rr0, rr1, rr2;
    kr0 = *reinterpret_cast<const uint4*>(kbase + (size_t)srow * 64 + sch * 8);
    vr0 = *reinterpret_cast<const uint4*>(vbase + (size_t)srow * KLEN + sch * 8);
    rr0 = *reinterpret_cast<const uint4*>(rbase + (size_t)(srow)       * 64 + sch * 8);
    rr1 = *reinterpret_cast<const uint4*>(rbase + (size_t)(srow + 64)  * 64 + sch * 8);
    rr2 = *reinterpret_cast<const uint4*>(rbase + (size_t)(srow + 128) * 64 + sch * 8);

    for (int jt = 0; jt < nj; ++jt) {
        const int j0 = jt * 64;
        __syncthreads();

        *reinterpret_cast<uint4*>((char*)Klds  + SWZ(srow,       sch * 16)) = kr0;
        *reinterpret_cast<uint4*>((char*)Vtlds + SWZ(srow,       sch * 16)) = vr0;
        *reinterpret_cast<uint4*>((char*)Rblds + SWZ(srow,       sch * 16)) = rr0;
        *reinterpret_cast<uint4*>((char*)Rblds + SWZ(srow + 64,  sch * 16)) = rr1;
        *reinterpret_cast<uint4*>((char*)Rblds + SWZ(srow + 128, sch * 16)) = rr2;

        if (jt + 1 < nj) {
            const int j1 = j0 + 64;
            kr0 = *reinterpret_cast<const uint4*>(kbase + (size_t)(j1 + srow) * 64 + sch * 8);
            vr0 = *reinterpret_cast<const uint4*>(vbase + (size_t)srow * KLEN + j1 + sch * 8);
            rr0 = *reinterpret_cast<const uint4*>(rbase + (size_t)(j1 + srow)       * 64 + sch * 8);
            rr1 = *reinterpret_cast<const uint4*>(rbase + (size_t)(j1 + srow + 64)  * 64 + sch * 8);
            rr2 = *reinterpret_cast<const uint4*>(rbase + (size_t)(j1 + srow + 128) * 64 + sch * 8);
        }

        asm volatile("s_waitcnt lgkmcnt(0)" ::: "memory");
        __builtin_amdgcn_sched_barrier(0);
        __builtin_amdgcn_s_barrier();
        asm volatile("" ::: "memory");
        __builtin_amdgcn_sched_barrier(0);

        __builtin_amdgcn_s_setprio(1);
        f32x4 sfr[4];
        #pragma unroll
        for (int bj = 0; bj < 4; ++bj) {
            f32x4 acc = (f32x4){0.f, 0.f, 0.f, 0.f};
            #pragma unroll
            for (int k = 0; k < 2; ++k) {
                bf16x8 bk = *reinterpret_cast<const bf16x8*>((const char*)Klds + SWZ(16 * bj + lc, 64 * k + 16 * lg));
                acc = __builtin_amdgcn_mfma_f32_16x16x32_bf16(aqw[k], bk, acc, 0, 0, 0);
            }
            sfr[bj] = acc;
        }
        f32x4 g[5];
        const int sb = 112 - 16 * w;
        #pragma unroll
        for (int cb = 0; cb < 5; ++cb) {
            g[cb] = (f32x4){0.f, 0.f, 0.f, 0.f};
            #pragma unroll
            for (int k = 0; k < 2; ++k) {
                bf16x8 br = *reinterpret_cast<const bf16x8*>((const char*)Rblds + SWZ(sb + 16 * cb + lc, 64 * k + 16 * lg));
                g[cb] = __builtin_amdgcn_mfma_f32_16x16x32_bf16(aqr[k], br, g[cb], 0, 0, 0);
            }
        }
        __builtin_amdgcn_s_setprio(0);

        #pragma unroll
        for (int reg = 0; reg < 4; ++reg) {
            int r = lg * 4 + reg;
            int srcl = (lane & 48) | ((lc - r + 15) & 15);
            float gg[5];
            #pragma unroll
            for (int cb = 0; cb < 5; ++cb)
                gg[cb] = __shfl(g[cb][reg], srcl, 64);
            #pragma unroll
            for (int bj = 0; bj < 4; ++bj) {
                float gv = (lc <= r) ? gg[bj] : gg[bj + 1];
                sfr[bj][reg] = sfr[bj][reg] + gv;
            }
        }
        if (jt >= nj - 2) {
            #pragma unroll
            for (int bj = 0; bj < 4; ++bj)
                #pragma unroll
                for (int reg = 0; reg < 4; ++reg) {
                    int ii = 16 * w + lg * 4 + reg;
                    int jj = 16 * bj + lc;
                    if (j0 + jj > i0 + ii + MLEN) sfr[bj][reg] = -1e30f;
                }
        }

        float pm[4];
        #pragma unroll
        for (int reg = 0; reg < 4; ++reg)
            pm[reg] = fmaxf(fmaxf(sfr[0][reg], sfr[1][reg]), fmaxf(sfr[2][reg], sfr[3][reg]));
        bool grow = (pm[0] > mreg[0] + RTHR) || (pm[1] > mreg[1] + RTHR) ||
                    (pm[2] > mreg[2] + RTHR) || (pm[3] > mreg[3] + RTHR);
        if (__any(grow)) {
            #pragma unroll
            for (int reg = 0; reg < 4; ++reg) {
                float gmax = pm[reg];
                gmax = fmaxf(gmax, __shfl_xor(gmax, 1));
                gmax = fmaxf(gmax, __shfl_xor(gmax, 2));
                gmax = fmaxf(gmax, __shfl_xor(gmax, 4));
                gmax = fmaxf(gmax, __shfl_xor(gmax, 8));
                float mo = mreg[reg], mn = fmaxf(mo, gmax);
                float fac = exp2f(mo - mn);
                lpart[reg] *= fac; tpart[reg] *= fac; mreg[reg] = mn;
                Ofr[0][reg] *= fac; Ofr[1][reg] *= fac;
                Ofr[2][reg] *= fac; Ofr[3][reg] *= fac;
            }
        }
        #pragma unroll
        for (int reg = 0; reg < 4; ++reg) {
            float mn = mreg[reg];
            int r = lg * 4 + reg;
            float ee[4];
            float le = 0.f, te = 0.f;
            #pragma unroll
            for (int bj = 0; bj < 4; ++bj) {
                ee[bj] = exp2f(sfr[bj][reg] - mn);
                le += ee[bj]; te += ee[bj] * sfr[bj][reg];
            }
            lpart[reg] += le;
            tpart[reg] += te;
            unsigned int p01, p23;
            asm("v_cvt_pk_bf16_f32 %0, %1, %2" : "=v"(p01) : "v"(ee[0]), "v"(ee[1]));
            asm("v_cvt_pk_bf16_f32 %0, %1, %2" : "=v"(p23) : "v"(ee[2]), "v"(ee[3]));
            *reinterpret_cast<unsigned int*>((char*)Plds + SWZ(16 * w + r, 4 * lc))      = p01;
            *reinterpret_cast<unsigned int*>((char*)Plds + SWZ(16 * w + r, 64 + 4 * lc)) = p23;
        }
        asm volatile("s_waitcnt lgkmcnt(0)" ::: "memory");
        __builtin_amdgcn_sched_barrier(0);

        __builtin_amdgcn_s_setprio(1);
        #pragma unroll
        for (int k = 0; k < 2; ++k) {
            bf16x8 ap = *reinterpret_cast<const bf16x8*>((const char*)Plds + SWZ(16 * w + lc, 64 * k + 16 * lg));
            Ofr[0] = __builtin_amdgcn_mfma_f32_16x16x32_bf16(ap,
                *reinterpret_cast<const bf16x8*>((const char*)Vtlds + SWZ( 0 + lc, 64 * k + 16 * lg)), Ofr[0], 0, 0, 0);
            Ofr[1] = __builtin_amdgcn_mfma_f32_16x16x32_bf16(ap,
                *reinterpret_cast<const bf16x8*>((const char*)Vtlds + SWZ(16 + lc, 64 * k + 16 * lg)), Ofr[1], 0, 0, 0);
            Ofr[2] = __builtin_amdgcn_mfma_f32_16x16x32_bf16(ap,
                *reinterpret_cast<const bf16x8*>((const char*)Vtlds + SWZ(32 + lc, 64 * k + 16 * lg)), Ofr[2], 0, 0, 0);
            Ofr[3] = __builtin_amdgcn_mfma_f32_16x16x32_bf16(ap,
                *reinterpret_cast<const bf16x8*>((const char*)Vtlds + SWZ(48 + lc, 64 * k + 16 * lg)), Ofr[3], 0, 0, 0);
        }
        __builtin_amdgcn_s_setprio(0);
    }

    float lred[4], tred[4];
    #pragma unroll
    for (int reg = 0; reg < 4; ++reg) {
        float l = lpart[reg], t = tpart[reg];
        l += __shfl_xor(l, 1); l += __shfl_xor(l, 2); l += __shfl_xor(l, 4); l += __shfl_xor(l, 8);
        t += __shfl_xor(t, 1); t += __shfl_xor(t, 2); t += __shfl_xor(t, 4); t += __shfl_xor(t, 8);
        lred[reg] = l; tred[reg] = t;
    }

    #pragma unroll
    for (int reg = 0; reg < 4; ++reg) {
        int i = i0 + 16 * w + lg * 4 + reg;
        float inv = 1.f / lred[reg];
        unsigned short* dst = AVB + ((size_t)i * BSZ + b) * DMODEL + n * 64 + lc;
        dst[ 0] = f2bf(Ofr[0][reg] * inv);
        dst[16] = f2bf(Ofr[1][reg] * inv);
        dst[32] = f2bf(Ofr[2][reg] * inv);
        dst[48] = f2bf(Ofr[3][reg] * inv);
    }

    float h = 0.f;
    if (lc == 0) {
        #pragma unroll
        for (int reg = 0; reg < 4; ++reg)
            h += mreg[reg] + log2f(lred[reg]) - tred[reg] / lred[reg];
    }
    h += __shfl_xor(h, 1);  h += __shfl_xor(h, 2);  h += __shfl_xor(h, 4);
    h += __shfl_xor(h, 8);  h += __shfl_xor(h, 16); h += __shfl_xor(h, 32);
    __syncthreads();
    float* hred = reinterpret_cast<float*>(Klds);
    if (lane == 0) hred[w] = h;
    __syncthreads();
    if (tid == 0) {
        float s = 0.f;
        #pragma unroll
        for (int q = 0; q < 8; ++q) s += hred[q];
        ENT[bn * 8 + iblk] = s * LN2F;
    }
}

extern "C" void kernel_launch(void* const* d_in, const int* in_sizes, int n_in,
                              void* d_out, int out_size, void* d_ws, size_t ws_size,
                              hipStream_t stream) {
    const float* w    = (const float*)d_in[0];
    const float* r    = (const float*)d_in[1];
    const float* rwb  = (const float*)d_in[2];
    const float* rrb  = (const float*)d_in[3];
    const float* mems = (const float*)d_in[4];
    const float* Wqkv = (const float*)d_in[6];
    const float* Wr   = (const float*)d_in[7];
    const float* Wo   = (const float*)d_in[8];
    float* out = (float*)d_out;
    char*  wsb = (char*)d_ws;

    unsigned short* QW  = (unsigned short*)(wsb + B_QW);
    unsigned short* QR  = (unsigned short*)(wsb + B_QR);
    unsigned short* Kg  = (unsigned short*)(wsb + B_K);
    unsigned short* VT  = (unsigned short*)(wsb + B_VT);
    unsigned short* Rg  = (unsigned short*)(wsb + B_R);
    unsigned short* AVB = (unsigned short*)(wsb + B_AVB);
    float* ENT = (float*)(wsb + B_ENT);
    unsigned short* WQT = (unsigned short*)(wsb + B_WQT);
    unsigned short* WRT = (unsigned short*)(wsb + B_WRT);
    unsigned short* WOT = (unsigned short*)(wsb + B_WOT);

    // weight transposes + R pad (one launch)
    tcvt3<<<dim3(48, 16, 4), 256, 0, stream>>>(Wqkv, Wr, Wo, WQT, WRT, WOT, Rg);

    // QKV + R projections (one launch; y>=128 blocks do R)
    gemm_mfma<0><<<dim3(12, 134), 256, 0, stream>>>(mems, w, r, nullptr, WQT, WRT, rwb, rrb,
                                                    QW, QR, Kg, VT, Rg, nullptr, nullptr);

    // attention + entropy partials
    attn_mfma<<<dim3(8, 64), 512, 0, stream>>>(QW, QR, Kg, VT, Rg, AVB, ENT);

    // out-projection + entropy reduce (one launch; y==64 block reduces ENT)
    gemm_mfma<2><<<dim3(4, 65), 256, 0, stream>>>(nullptr, nullptr, nullptr, AVB, WOT, nullptr,
                                                  nullptr, nullptr, nullptr, nullptr, nullptr,
                                                  nullptr, nullptr, ENT, out);
}